// Round 7
// baseline (232.707 us; speedup 1.0000x reference)
//
#include <hip/hip_runtime.h>
#include <stdint.h>

typedef unsigned short u16;
typedef __attribute__((ext_vector_type(8))) short bf16x8;   // 8 bf16 in 4 VGPRs
typedef __attribute__((ext_vector_type(4))) float f32x4;

#define B_   16
#define C_   256
#define HW_  4096
#define QR_  384
#define HID_ 128

__device__ __forceinline__ float b2f(u16 u) {
  union { uint32_t i; float f; } v; v.i = ((uint32_t)u) << 16; return v.f;
}
__device__ __forceinline__ u16 f2b(float f) {
  union { float f; uint32_t i; } v; v.f = f;
  uint32_t r = (v.i + 0x7FFFu + ((v.i >> 16) & 1u)) >> 16;
  return (u16)r;
}

// ---------------------------------------------------------------------------
// K1: heterogeneous. blocks [0,512): GroupNorm stats -> per-(b,c) scale/shift.
// blocks [512,608): convert qkv_w fp32 -> bf16. block 608: build WqT bf16
// [256 c][128 d]. blocks [609,675): zero ctx/s atomic accumulators.
// ---------------------------------------------------------------------------
__global__ __launch_bounds__(256) void gn_stats_conv_kernel(
    const float* __restrict__ x, const float* __restrict__ gnw,
    const float* __restrict__ gnb, float* __restrict__ scale,
    float* __restrict__ shiftv,
    const float* __restrict__ qkvw, u16* __restrict__ cqkvw,
    u16* __restrict__ wqT, float* __restrict__ ctxs)
{
  if (blockIdx.x >= 512) {
    int bi = blockIdx.x - 512;
    int t = threadIdx.x;
    if (bi < 96) {
      int i = bi * 256 + t;                       // < 24576 exactly
      float4 f = ((const float4*)qkvw)[i];
      ushort4 o;
      o.x = f2b(f.x); o.y = f2b(f.y); o.z = f2b(f.z); o.w = f2b(f.w);
      ((ushort4*)cqkvw)[i] = o;
      return;
    }
    if (bi >= 97) {
      int z = (bi - 97) * 256 + t;                // < 16896 exactly
      ((float4*)ctxs)[z] = make_float4(0.f, 0.f, 0.f, 0.f);
      return;
    }
    // bi == 96: WqT[c][d] = bf16(Wq[d][c]).
    __shared__ u16 tl[16][272];
    for (int j = 0; j < 8; ++j) {
      int d = j * 16 + (t >> 4);
      int cb = (t & 15) * 16;
#pragma unroll
      for (int ii = 0; ii < 16; ++ii)
        tl[t >> 4][cb + ii] = f2b(qkvw[(size_t)d * 256 + cb + ii]);
      __syncthreads();
      union { u16 v[16]; uint4 q[2]; } pk;
#pragma unroll
      for (int dd = 0; dd < 16; ++dd) pk.v[dd] = tl[dd][t];
      *(uint4*)(wqT + (size_t)t * 128 + j * 16)     = pk.q[0];
      *(uint4*)(wqT + (size_t)t * 128 + j * 16 + 8) = pk.q[1];
      __syncthreads();
    }
    return;
  }
  int b = blockIdx.x >> 5, g = blockIdx.x & 31;
  const float* p = x + ((size_t)b * C_ + g * 8) * HW_;
  int t = threadIdx.x;
  float s = 0.f, sq = 0.f;
#pragma unroll
  for (int i = 0; i < 16; ++i) {
    float4 u0 = *(const float4*)(p + t * 8 + i * 2048);
    float4 u1 = *(const float4*)(p + t * 8 + i * 2048 + 4);
    s  += u0.x + u0.y + u0.z + u0.w + u1.x + u1.y + u1.z + u1.w;
    sq += u0.x*u0.x + u0.y*u0.y + u0.z*u0.z + u0.w*u0.w
        + u1.x*u1.x + u1.y*u1.y + u1.z*u1.z + u1.w*u1.w;
  }
#pragma unroll
  for (int off = 32; off > 0; off >>= 1) {
    s  += __shfl_down(s, off);
    sq += __shfl_down(sq, off);
  }
  __shared__ float ps[4], pq[4], mr[2];
  int lane = t & 63, w = t >> 6;
  if (lane == 0) { ps[w] = s; pq[w] = sq; }
  __syncthreads();
  if (t == 0) {
    float S = ps[0] + ps[1] + ps[2] + ps[3];
    float Q = pq[0] + pq[1] + pq[2] + pq[3];
    float mean = S * (1.f / 32768.f);
    float var  = Q * (1.f / 32768.f) - mean * mean;
    mr[0] = mean; mr[1] = rsqrtf(var + 1e-5f);
  }
  __syncthreads();
  if (t < 8) {
    int c = g * 8 + t;
    float sc = gnw[c] * mr[1];
    scale[b * C_ + c]  = sc;
    shiftv[b * C_ + c] = gnb[c] - mr[0] * sc;
  }
}

// ---------------------------------------------------------------------------
// K2: fused GN-apply + transpose: x fp32 [b][256][4096] -> xn_t bf16
// [b][4096][256]. tile 64 c x 128 n, grid (32, 4, 16).
// ---------------------------------------------------------------------------
__global__ __launch_bounds__(256) void gn_transpose_kernel(
    const float* __restrict__ x, u16* __restrict__ dst,
    const float* __restrict__ scale, const float* __restrict__ shiftv)
{
  int nt = blockIdx.x, ct = blockIdx.y, b = blockIdx.z;
  const float* S = x + (size_t)b * C_ * HW_;
  u16* D = dst + (size_t)b * HW_ * C_;
  __shared__ __align__(16) u16 tile[64][136];
  int t = threadIdx.x;
  int n0 = nt * 128, c0 = ct * 64;
  int r = t >> 2, seg = (t & 3) * 32;
  float sc = scale[(size_t)b * C_ + c0 + r];
  float sh = shiftv[(size_t)b * C_ + c0 + r];
#pragma unroll
  for (int i = 0; i < 4; ++i) {
    const float* rp = S + (size_t)(c0 + r) * HW_ + n0 + seg + i * 8;
    float4 u0 = *(const float4*)(rp);
    float4 u1 = *(const float4*)(rp + 4);
    float f[8] = {u0.x, u0.y, u0.z, u0.w, u1.x, u1.y, u1.z, u1.w};
    uint4 o;
    uint32_t* op = (uint32_t*)&o;
#pragma unroll
    for (int j = 0; j < 4; ++j) {
      op[j] = (uint32_t)f2b(f[2 * j] * sc + sh)
            | ((uint32_t)f2b(f[2 * j + 1] * sc + sh) << 16);
    }
    *(uint4*)&tile[r][seg + i * 8] = o;
  }
  __syncthreads();
#pragma unroll
  for (int i = 0; i < 4; ++i) {
    int m = t * 4 + i;
    int n_l = m >> 3, cg = (m & 7) * 8;
    union { u16 v[8]; uint4 q; } pk;
#pragma unroll
    for (int e = 0; e < 8; ++e) pk.v[e] = tile[cg + e][n_l];
    *(uint4*)(D + (size_t)(n0 + n_l) * C_ + c0 + cg) = pk.q;
  }
}

// ---------------------------------------------------------------------------
// K3: fused kv-GEMM + exp + partial context. grid (32,16), 512 thr (8 waves).
// Waves 0-3 compute k rows (no bias: cancels in softmax), waves 4-7 v rows
// (no bias: folded later since sum p = 1). Epilogue: exp(k) in-register,
// expk & v staged to padded LDS, per-head 32x32 partial context via MFMA;
// partials accumulated with device atomicAdd into ctx[b][4][1024], s[b][128].
// ---------------------------------------------------------------------------
__global__ __launch_bounds__(512) void kv_ctx_kernel(
    const u16* __restrict__ A,      // cqkvw + 128*256 (k rows then v rows)
    const u16* __restrict__ Bt,     // xn_t
    float* __restrict__ ctx,        // [b][4][1024] atomic accumulator
    float* __restrict__ sv)         // [b][128]     atomic accumulator
{
  const int K = C_;
  int nt = blockIdx.x, b = blockIdx.y;
  const u16* Ab = A;
  const u16* Bb = Bt + (size_t)b * HW_ * C_ + (size_t)nt * 128 * K;
  __shared__ __align__(16) union {
    struct { u16 lA[256 * 64]; u16 lB[128 * 64]; } st;            // 48 KB
    struct { u16 ek[128][136]; u16 vv[128][136]; float sred[2][128]; } ep; // ~69 KB
    float cred[4096];                                             // 16 KB
  } sm;
  int t = threadIdx.x;
  int lane = t & 63, w = t >> 6;
  int quad = lane >> 4, l16 = lane & 15;
  int wm = (w >> 1) * 64, wn = (w & 1) * 64;   // rows 0-127 = k, 128-255 = v
  f32x4 acc[4][4];
#pragma unroll
  for (int i = 0; i < 4; ++i)
#pragma unroll
    for (int j = 0; j < 4; ++j)
#pragma unroll
      for (int r = 0; r < 4; ++r) acc[i][j][r] = 0.f;

  for (int k0 = 0; k0 < K; k0 += 64) {
    __syncthreads();
#pragma unroll
    for (int q = 0; q < 4; ++q) {
      int ch = q * 512 + t;            // 2048 chunks: A is 256 rows x 64
      int row = ch >> 3, off = (ch & 7) * 8;
      __builtin_amdgcn_global_load_lds(
          (const __attribute__((address_space(1))) void*)(Ab + (size_t)row * K + k0 + off),
          (__attribute__((address_space(3))) void*)(sm.st.lA + ch * 8), 16, 0, 0);
    }
#pragma unroll
    for (int q = 0; q < 2; ++q) {
      int ch = q * 512 + t;            // 1024 chunks: B is 128 rows x 64
      int row = ch >> 3, off = (ch & 7) * 8;
      __builtin_amdgcn_global_load_lds(
          (const __attribute__((address_space(1))) void*)(Bb + (size_t)row * K + k0 + off),
          (__attribute__((address_space(3))) void*)(sm.st.lB + ch * 8), 16, 0, 0);
    }
    __syncthreads();
    const bf16x8* A8 = (const bf16x8*)sm.st.lA;
    const bf16x8* B8 = (const bf16x8*)sm.st.lB;
#pragma unroll
    for (int kk = 0; kk < 2; ++kk) {
      bf16x8 af[4], bfr[4];
#pragma unroll
      for (int i = 0; i < 4; ++i) af[i]  = A8[(wm + i * 16 + l16) * 8 + kk * 4 + quad];
#pragma unroll
      for (int j = 0; j < 4; ++j) bfr[j] = B8[(wn + j * 16 + l16) * 8 + kk * 4 + quad];
#pragma unroll
      for (int i = 0; i < 4; ++i)
#pragma unroll
        for (int j = 0; j < 4; ++j)
          acc[i][j] = __builtin_amdgcn_mfma_f32_16x16x32_bf16(af[i], bfr[j],
                                                              acc[i][j], 0, 0, 0);
    }
  }

  // ---- epilogue: exp / stage to padded LDS -------------------------------
  __syncthreads();                     // staging LDS dead; switch to ep view
  int h = w >> 1, nh = w & 1;
  if (w < 4) {
    float sl[4][4];
#pragma unroll
    for (int i = 0; i < 4; ++i)
#pragma unroll
      for (int r = 0; r < 4; ++r) sl[i][r] = 0.f;
#pragma unroll
    for (int i = 0; i < 4; ++i)
#pragma unroll
      for (int j = 0; j < 4; ++j)
#pragma unroll
        for (int r = 0; r < 4; ++r) {
          float e = __expf(acc[i][j][r]);
          sl[i][r] += e;
          sm.ep.ek[wm + i * 16 + quad * 4 + r][wn + j * 16 + l16] = f2b(e);
        }
#pragma unroll
    for (int i = 0; i < 4; ++i)
#pragma unroll
      for (int r = 0; r < 4; ++r) {
        float v = sl[i][r];
        v += __shfl_xor(v, 1);
        v += __shfl_xor(v, 2);
        v += __shfl_xor(v, 4);
        v += __shfl_xor(v, 8);
        if (l16 == 0) sm.ep.sred[nh][wm + i * 16 + quad * 4 + r] = v;
      }
  } else {
#pragma unroll
    for (int i = 0; i < 4; ++i)
#pragma unroll
      for (int j = 0; j < 4; ++j)
#pragma unroll
        for (int r = 0; r < 4; ++r)
          sm.ep.vv[wm - 128 + i * 16 + quad * 4 + r][wn + j * 16 + l16] =
              f2b(acc[i][j][r]);
  }
  __syncthreads();
  if (t < 128)
    atomicAdd(&sv[(size_t)b * 128 + t], sm.ep.sred[0][t] + sm.ep.sred[1][t]);

  // ---- partial context: wave w -> head h = w>>1, spatial half nh = w&1 ----
  f32x4 c2[2][2];
#pragma unroll
  for (int i = 0; i < 2; ++i)
#pragma unroll
    for (int j = 0; j < 2; ++j)
#pragma unroll
      for (int r = 0; r < 4; ++r) c2[i][j][r] = 0.f;
#pragma unroll
  for (int kk = 0; kk < 2; ++kk) {
    bf16x8 ae[2], be[2];
#pragma unroll
    for (int i = 0; i < 2; ++i)
      ae[i] = *(const bf16x8*)&sm.ep.ek[h * 32 + i * 16 + l16][nh * 64 + kk * 32 + quad * 8];
#pragma unroll
    for (int j = 0; j < 2; ++j)
      be[j] = *(const bf16x8*)&sm.ep.vv[h * 32 + j * 16 + l16][nh * 64 + kk * 32 + quad * 8];
#pragma unroll
    for (int i = 0; i < 2; ++i)
#pragma unroll
      for (int j = 0; j < 2; ++j)
        c2[i][j] = __builtin_amdgcn_mfma_f32_16x16x32_bf16(ae[i], be[j], c2[i][j], 0, 0, 0);
  }
  __syncthreads();                     // ek/vv reads done; alias cred
  if (nh == 0) {
#pragma unroll
    for (int i = 0; i < 2; ++i)
#pragma unroll
      for (int j = 0; j < 2; ++j)
#pragma unroll
        for (int r = 0; r < 4; ++r)
          sm.cred[h * 1024 + (i * 16 + quad * 4 + r) * 32 + j * 16 + l16] = c2[i][j][r];
  }
  __syncthreads();
  if (nh == 1) {
#pragma unroll
    for (int i = 0; i < 2; ++i)
#pragma unroll
      for (int j = 0; j < 2; ++j)
#pragma unroll
        for (int r = 0; r < 4; ++r)
          sm.cred[h * 1024 + (i * 16 + quad * 4 + r) * 32 + j * 16 + l16] += c2[i][j][r];
  }
  __syncthreads();
  float* ctxb = ctx + (size_t)b * 4096;
#pragma unroll
  for (int u = 0; u < 8; ++u)
    atomicAdd(&ctxb[t + u * 512], sm.cred[t + u * 512]);
}

// ---------------------------------------------------------------------------
// K4: fold + Wtot, fence-free. grid 16 = b, 256 thr. One block per batch:
// stage reduced ctx[b] (16 KB) + sinv; fold all 4 heads -> wf entirely in
// LDS (never global); btot[b][o] = outb + wf·bq; Wtot[b] = wf @ WqT^T via
// 4-wave MFMA. K3->K4 visibility via kernel boundary (no fences needed).
// ---------------------------------------------------------------------------
__global__ __launch_bounds__(256) void foldwtot_kernel(
    const float* __restrict__ ctx, const float* __restrict__ sv,
    const float* __restrict__ outw, const float* __restrict__ qkvb,
    const u16* __restrict__ wqT, const float* __restrict__ outb,
    u16* __restrict__ wtot, float* __restrict__ btot)
{
  int b = blockIdx.x;
  int t = threadIdx.x;
  __shared__ float cs[4096];                     // ctx[b]: [h][d*32+e]
  __shared__ float sinv[128];
  __shared__ __align__(16) u16 wfl[256 * 136];   // wf[b] padded: stride 136
  const float4* cp = (const float4*)(ctx + (size_t)b * 4096);
  float4* cs4 = (float4*)cs;
#pragma unroll
  for (int i = 0; i < 4; ++i) cs4[t + i * 256] = cp[t + i * 256];
  if (t < 128) sinv[t] = 1.f / sv[(size_t)b * 128 + t];
  __syncthreads();

  // ---- fold: thread t = o, all 4 heads; wf rows stay in LDS --------------
  {
    int o = t;
#pragma unroll
    for (int h = 0; h < 4; ++h) {
      const float* wr = outw + (size_t)o * HID_ + h * 32;
      float wv[32];
      float cb = 0.f;
#pragma unroll
      for (int e = 0; e < 32; ++e) {
        wv[e] = wr[e];
        cb += wv[e] * qkvb[256 + h * 32 + e];   // v-bias term, d-independent
      }
      union { u16 v[32]; uint4 q[4]; } pk;
#pragma unroll
      for (int d = 0; d < 32; ++d) {
        float a = 0.f;
#pragma unroll
        for (int e = 0; e < 32; ++e) a += wv[e] * cs[h * 1024 + d * 32 + e];
        pk.v[d] = f2b(a * sinv[h * 32 + d] + cb);
      }
#pragma unroll
      for (int i = 0; i < 4; ++i)
        *(uint4*)&wfl[o * 136 + h * 32 + i * 8] = pk.q[i];
    }
  }
  __syncthreads();

  // ---- btot[b][o] = outb[o] + sum_d wf[o][d] * bq[d] ---------------------
  {
    float a = outb[t];
#pragma unroll
    for (int i = 0; i < 16; ++i) {
      union { uint4 q; u16 v[8]; } u;
      u.q = *(const uint4*)&wfl[t * 136 + i * 8];
#pragma unroll
      for (int e = 0; e < 8; ++e) a += b2f(u.v[e]) * qkvb[i * 8 + e];
    }
    btot[(size_t)b * C_ + t] = a;
  }

  // ---- Wtot[b][o][c] = sum_d wf[o][d] * wqT[c][d]; wave w: o [w*64,+64) --
  int lane = t & 63, w = t >> 6;
  int quad = lane >> 4, l16 = lane & 15;
  u16* Wb = wtot + (size_t)b * C_ * C_;
  for (int j = 0; j < 16; ++j) {          // c-frags
    f32x4 a4[4];
#pragma unroll
    for (int i = 0; i < 4; ++i)
#pragma unroll
      for (int r = 0; r < 4; ++r) a4[i][r] = 0.f;
#pragma unroll
    for (int kk = 0; kk < 4; ++kk) {
      bf16x8 bfj = *(const bf16x8*)(wqT + (size_t)(j * 16 + l16) * 128 + kk * 32 + quad * 8);
#pragma unroll
      for (int i = 0; i < 4; ++i) {
        bf16x8 afi = *(const bf16x8*)&wfl[(w * 64 + i * 16 + l16) * 136 + kk * 32 + quad * 8];
        a4[i] = __builtin_amdgcn_mfma_f32_16x16x32_bf16(bfj, afi, a4[i], 0, 0, 0);
      }
    }
    // D[c-local = quad*4+r][o-local = l16]: pack 4 consecutive c per lane
#pragma unroll
    for (int i = 0; i < 4; ++i) {
      int oo = w * 64 + i * 16 + l16;
      int c0 = j * 16 + quad * 4;
      uint2 p2;
      p2.x = (uint32_t)f2b(a4[i][0]) | ((uint32_t)f2b(a4[i][1]) << 16);
      p2.y = (uint32_t)f2b(a4[i][2]) | ((uint32_t)f2b(a4[i][3]) << 16);
      *(uint2*)(Wb + (size_t)oo * C_ + c0) = p2;
    }
  }
}

// ---------------------------------------------------------------------------
// K5: final GEMM. out = Wtot(bf16 256x256) @ xn_t^T (+btot), fp32 out.
// 128x128 tile, BK=64, K=256. grid (32, 2, 16). Swapped MFMA operands:
// acc rows = n -> float4 stores (one 64B line per row per instruction).
// ---------------------------------------------------------------------------
__global__ __launch_bounds__(256) void out_gemm_kernel(
    const u16* __restrict__ wtot, const u16* __restrict__ Bt,
    const float* __restrict__ btot, float* __restrict__ Cout)
{
  const int K = C_;
  int nt = blockIdx.x, mt = blockIdx.y, b = blockIdx.z;
  const u16* Ab = wtot + (size_t)b * C_ * C_ + (size_t)mt * 128 * K;
  const u16* Bb = Bt + (size_t)b * HW_ * C_ + (size_t)nt * 128 * K;
  __shared__ __align__(16) u16 lA[128 * 64];
  __shared__ __align__(16) u16 lB[128 * 64];
  int t = threadIdx.x;
  int lane = t & 63, w = t >> 6;
  int quad = lane >> 4, l16 = lane & 15;
  int wm = (w >> 1) * 64, wn = (w & 1) * 64;
  f32x4 acc[4][4];                       // [j: n-frag][i: o-frag]
#pragma unroll
  for (int j = 0; j < 4; ++j)
#pragma unroll
    for (int i = 0; i < 4; ++i)
#pragma unroll
      for (int r = 0; r < 4; ++r) acc[j][i][r] = 0.f;

  for (int k0 = 0; k0 < K; k0 += 64) {
    __syncthreads();
#pragma unroll
    for (int q = 0; q < 4; ++q) {
      int ch = q * 256 + t;
      int row = ch >> 3, off = (ch & 7) * 8;
      __builtin_amdgcn_global_load_lds(
          (const __attribute__((address_space(1))) void*)(Ab + (size_t)row * K + k0 + off),
          (__attribute__((address_space(3))) void*)(lA + ch * 8), 16, 0, 0);
      __builtin_amdgcn_global_load_lds(
          (const __attribute__((address_space(1))) void*)(Bb + (size_t)row * K + k0 + off),
          (__attribute__((address_space(3))) void*)(lB + ch * 8), 16, 0, 0);
    }
    __syncthreads();
    const bf16x8* A8 = (const bf16x8*)lA;
    const bf16x8* B8 = (const bf16x8*)lB;
#pragma unroll
    for (int kk = 0; kk < 2; ++kk) {
      bf16x8 af[4], bfr[4];
#pragma unroll
      for (int i = 0; i < 4; ++i) af[i]  = A8[(wm + i * 16 + l16) * 8 + kk * 4 + quad];
#pragma unroll
      for (int j = 0; j < 4; ++j) bfr[j] = B8[(wn + j * 16 + l16) * 8 + kk * 4 + quad];
#pragma unroll
      for (int j = 0; j < 4; ++j)
#pragma unroll
        for (int i = 0; i < 4; ++i)
          acc[j][i] = __builtin_amdgcn_mfma_f32_16x16x32_bf16(bfr[j], af[i],
                                                              acc[j][i], 0, 0, 0);
    }
  }
  // D[row = n-local (quad*4+r)][col = o-local (l16)]
#pragma unroll
  for (int i = 0; i < 4; ++i) {
    int o = mt * 128 + wm + i * 16 + l16;
    float bo = btot[(size_t)b * C_ + o];
    size_t rowbase = (size_t)b * C_ * HW_ + (size_t)o * HW_;
#pragma unroll
    for (int j = 0; j < 4; ++j) {
      int n0 = nt * 128 + wn + j * 16 + quad * 4;
      float4 v = make_float4(acc[j][i][0] + bo, acc[j][i][1] + bo,
                             acc[j][i][2] + bo, acc[j][i][3] + bo);
      *(float4*)(Cout + rowbase + n0) = v;
    }
  }
}

// ---------------------------------------------------------------------------
extern "C" void kernel_launch(void* const* d_in, const int* in_sizes, int n_in,
                              void* d_out, int out_size, void* d_ws, size_t ws_size,
                              hipStream_t stream)
{
  const float* x    = (const float*)d_in[0];
  const float* gnw  = (const float*)d_in[1];
  const float* gnb  = (const float*)d_in[2];
  const float* qkvw = (const float*)d_in[3];
  const float* qkvb = (const float*)d_in[4];
  const float* outw = (const float*)d_in[5];
  const float* outb = (const float*)d_in[6];

  char* p = (char*)d_ws;
  float* scale  = (float*)p;            p += (size_t)B_ * C_ * 4;
  float* shiftv = (float*)p;            p += (size_t)B_ * C_ * 4;
  u16* cqkvw = (u16*)p;                 p += (size_t)QR_ * C_ * 2;
  u16* wqT   = (u16*)p;                 p += (size_t)C_ * HID_ * 2;
  u16* xn_t  = (u16*)p;                 p += (size_t)B_ * HW_ * C_ * 2;
  u16* wtot  = (u16*)p;                 p += (size_t)B_ * C_ * C_ * 2;
  float* ctxs = (float*)p;              p += (size_t)67584 * 4;   // ctx 65536 + s 2048
  float* btot = (float*)p;
  float* ctx = ctxs;
  float* sv  = ctxs + 65536;

  gn_stats_conv_kernel<<<675, 256, 0, stream>>>(x, gnw, gnb, scale, shiftv,
                                                qkvw, cqkvw, wqT, ctxs);
  gn_transpose_kernel<<<dim3(32, 4, 16), 256, 0, stream>>>(x, xn_t, scale, shiftv);
  kv_ctx_kernel<<<dim3(32, 16), 512, 0, stream>>>(cqkvw + 128 * C_, xn_t, ctx, sv);
  foldwtot_kernel<<<16, 256, 0, stream>>>(ctx, sv, outw, qkvb, wqT, outb,
                                          wtot, btot);
  out_gemm_kernel<<<dim3(32, 2, 16), 256, 0, stream>>>(wtot, xn_t, btot,
                                                       (float*)d_out);
}

// Round 8
// 195.023 us; speedup vs baseline: 1.1932x; 1.1932x over previous
//
#include <hip/hip_runtime.h>
#include <stdint.h>

typedef unsigned short u16;
typedef __attribute__((ext_vector_type(8))) short bf16x8;   // 8 bf16 in 4 VGPRs
typedef __attribute__((ext_vector_type(4))) float f32x4;

#define B_   16
#define C_   256
#define HW_  4096
#define QR_  384
#define HID_ 128

__device__ __forceinline__ float b2f(u16 u) {
  union { uint32_t i; float f; } v; v.i = ((uint32_t)u) << 16; return v.f;
}
__device__ __forceinline__ u16 f2b(float f) {
  union { float f; uint32_t i; } v; v.f = f;
  uint32_t r = (v.i + 0x7FFFu + ((v.i >> 16) & 1u)) >> 16;
  return (u16)r;
}

// ---------------------------------------------------------------------------
// K1: heterogeneous. blocks [0,512): GroupNorm stats -> per-(b,c) scale/shift.
// blocks [512,608): convert qkv_w fp32 -> bf16. block 608: build WqT bf16
// [256 c][128 d]. blocks [609,675): zero ctx/s atomic accumulators.
// ---------------------------------------------------------------------------
__global__ __launch_bounds__(256) void gn_stats_conv_kernel(
    const float* __restrict__ x, const float* __restrict__ gnw,
    const float* __restrict__ gnb, float* __restrict__ scale,
    float* __restrict__ shiftv,
    const float* __restrict__ qkvw, u16* __restrict__ cqkvw,
    u16* __restrict__ wqT, float* __restrict__ ctxs)
{
  if (blockIdx.x >= 512) {
    int bi = blockIdx.x - 512;
    int t = threadIdx.x;
    if (bi < 96) {
      int i = bi * 256 + t;                       // < 24576 exactly
      float4 f = ((const float4*)qkvw)[i];
      ushort4 o;
      o.x = f2b(f.x); o.y = f2b(f.y); o.z = f2b(f.z); o.w = f2b(f.w);
      ((ushort4*)cqkvw)[i] = o;
      return;
    }
    if (bi >= 97) {
      int z = (bi - 97) * 256 + t;                // < 16896 exactly
      ((float4*)ctxs)[z] = make_float4(0.f, 0.f, 0.f, 0.f);
      return;
    }
    // bi == 96: WqT[c][d] = bf16(Wq[d][c]).
    __shared__ u16 tl[16][272];
    for (int j = 0; j < 8; ++j) {
      int d = j * 16 + (t >> 4);
      int cb = (t & 15) * 16;
#pragma unroll
      for (int ii = 0; ii < 16; ++ii)
        tl[t >> 4][cb + ii] = f2b(qkvw[(size_t)d * 256 + cb + ii]);
      __syncthreads();
      union { u16 v[16]; uint4 q[2]; } pk;
#pragma unroll
      for (int dd = 0; dd < 16; ++dd) pk.v[dd] = tl[dd][t];
      *(uint4*)(wqT + (size_t)t * 128 + j * 16)     = pk.q[0];
      *(uint4*)(wqT + (size_t)t * 128 + j * 16 + 8) = pk.q[1];
      __syncthreads();
    }
    return;
  }
  int b = blockIdx.x >> 5, g = blockIdx.x & 31;
  const float* p = x + ((size_t)b * C_ + g * 8) * HW_;
  int t = threadIdx.x;
  float s = 0.f, sq = 0.f;
#pragma unroll
  for (int i = 0; i < 16; ++i) {
    float4 u0 = *(const float4*)(p + t * 8 + i * 2048);
    float4 u1 = *(const float4*)(p + t * 8 + i * 2048 + 4);
    s  += u0.x + u0.y + u0.z + u0.w + u1.x + u1.y + u1.z + u1.w;
    sq += u0.x*u0.x + u0.y*u0.y + u0.z*u0.z + u0.w*u0.w
        + u1.x*u1.x + u1.y*u1.y + u1.z*u1.z + u1.w*u1.w;
  }
#pragma unroll
  for (int off = 32; off > 0; off >>= 1) {
    s  += __shfl_down(s, off);
    sq += __shfl_down(sq, off);
  }
  __shared__ float ps[4], pq[4], mr[2];
  int lane = t & 63, w = t >> 6;
  if (lane == 0) { ps[w] = s; pq[w] = sq; }
  __syncthreads();
  if (t == 0) {
    float S = ps[0] + ps[1] + ps[2] + ps[3];
    float Q = pq[0] + pq[1] + pq[2] + pq[3];
    float mean = S * (1.f / 32768.f);
    float var  = Q * (1.f / 32768.f) - mean * mean;
    mr[0] = mean; mr[1] = rsqrtf(var + 1e-5f);
  }
  __syncthreads();
  if (t < 8) {
    int c = g * 8 + t;
    float sc = gnw[c] * mr[1];
    scale[b * C_ + c]  = sc;
    shiftv[b * C_ + c] = gnb[c] - mr[0] * sc;
  }
}

// ---------------------------------------------------------------------------
// K2: fused GN-apply + transpose: x fp32 [b][256][4096] -> xn_t bf16
// [b][4096][256]. tile 64 c x 128 n, grid (32, 4, 16).
// ---------------------------------------------------------------------------
__global__ __launch_bounds__(256) void gn_transpose_kernel(
    const float* __restrict__ x, u16* __restrict__ dst,
    const float* __restrict__ scale, const float* __restrict__ shiftv)
{
  int nt = blockIdx.x, ct = blockIdx.y, b = blockIdx.z;
  const float* S = x + (size_t)b * C_ * HW_;
  u16* D = dst + (size_t)b * HW_ * C_;
  __shared__ __align__(16) u16 tile[64][136];
  int t = threadIdx.x;
  int n0 = nt * 128, c0 = ct * 64;
  int r = t >> 2, seg = (t & 3) * 32;
  float sc = scale[(size_t)b * C_ + c0 + r];
  float sh = shiftv[(size_t)b * C_ + c0 + r];
#pragma unroll
  for (int i = 0; i < 4; ++i) {
    const float* rp = S + (size_t)(c0 + r) * HW_ + n0 + seg + i * 8;
    float4 u0 = *(const float4*)(rp);
    float4 u1 = *(const float4*)(rp + 4);
    float f[8] = {u0.x, u0.y, u0.z, u0.w, u1.x, u1.y, u1.z, u1.w};
    uint4 o;
    uint32_t* op = (uint32_t*)&o;
#pragma unroll
    for (int j = 0; j < 4; ++j) {
      op[j] = (uint32_t)f2b(f[2 * j] * sc + sh)
            | ((uint32_t)f2b(f[2 * j + 1] * sc + sh) << 16);
    }
    *(uint4*)&tile[r][seg + i * 8] = o;
  }
  __syncthreads();
#pragma unroll
  for (int i = 0; i < 4; ++i) {
    int m = t * 4 + i;
    int n_l = m >> 3, cg = (m & 7) * 8;
    union { u16 v[8]; uint4 q; } pk;
#pragma unroll
    for (int e = 0; e < 8; ++e) pk.v[e] = tile[cg + e][n_l];
    *(uint4*)(D + (size_t)(n0 + n_l) * C_ + c0 + cg) = pk.q;
  }
}

// ---------------------------------------------------------------------------
// K3: fused kv-GEMM + exp + partial context. grid (32,16), 512 thr (8 waves).
// Waves 0-3 compute k rows (no bias: cancels in softmax), waves 4-7 v rows
// (no bias: folded later since sum p = 1). Epilogue: exp(k) in-register,
// expk & v staged to padded LDS, per-head 32x32 partial context via MFMA;
// partials accumulated with device atomicAdd into ctx[b][4][1024], s[b][128].
// ---------------------------------------------------------------------------
__global__ __launch_bounds__(512) void kv_ctx_kernel(
    const u16* __restrict__ A,      // cqkvw + 128*256 (k rows then v rows)
    const u16* __restrict__ Bt,     // xn_t
    float* __restrict__ ctx,        // [b][4][1024] atomic accumulator
    float* __restrict__ sv)         // [b][128]     atomic accumulator
{
  const int K = C_;
  int nt = blockIdx.x, b = blockIdx.y;
  const u16* Ab = A;
  const u16* Bb = Bt + (size_t)b * HW_ * C_ + (size_t)nt * 128 * K;
  __shared__ __align__(16) union {
    struct { u16 lA[256 * 64]; u16 lB[128 * 64]; } st;            // 48 KB
    struct { u16 ek[128][136]; u16 vv[128][136]; float sred[2][128]; } ep; // ~69 KB
    float cred[4096];                                             // 16 KB
  } sm;
  int t = threadIdx.x;
  int lane = t & 63, w = t >> 6;
  int quad = lane >> 4, l16 = lane & 15;
  int wm = (w >> 1) * 64, wn = (w & 1) * 64;   // rows 0-127 = k, 128-255 = v
  f32x4 acc[4][4];
#pragma unroll
  for (int i = 0; i < 4; ++i)
#pragma unroll
    for (int j = 0; j < 4; ++j)
#pragma unroll
      for (int r = 0; r < 4; ++r) acc[i][j][r] = 0.f;

  for (int k0 = 0; k0 < K; k0 += 64) {
    __syncthreads();
#pragma unroll
    for (int q = 0; q < 4; ++q) {
      int ch = q * 512 + t;            // 2048 chunks: A is 256 rows x 64
      int row = ch >> 3, off = (ch & 7) * 8;
      __builtin_amdgcn_global_load_lds(
          (const __attribute__((address_space(1))) void*)(Ab + (size_t)row * K + k0 + off),
          (__attribute__((address_space(3))) void*)(sm.st.lA + ch * 8), 16, 0, 0);
    }
#pragma unroll
    for (int q = 0; q < 2; ++q) {
      int ch = q * 512 + t;            // 1024 chunks: B is 128 rows x 64
      int row = ch >> 3, off = (ch & 7) * 8;
      __builtin_amdgcn_global_load_lds(
          (const __attribute__((address_space(1))) void*)(Bb + (size_t)row * K + k0 + off),
          (__attribute__((address_space(3))) void*)(sm.st.lB + ch * 8), 16, 0, 0);
    }
    __syncthreads();
    const bf16x8* A8 = (const bf16x8*)sm.st.lA;
    const bf16x8* B8 = (const bf16x8*)sm.st.lB;
#pragma unroll
    for (int kk = 0; kk < 2; ++kk) {
      bf16x8 af[4], bfr[4];
#pragma unroll
      for (int i = 0; i < 4; ++i) af[i]  = A8[(wm + i * 16 + l16) * 8 + kk * 4 + quad];
#pragma unroll
      for (int j = 0; j < 4; ++j) bfr[j] = B8[(wn + j * 16 + l16) * 8 + kk * 4 + quad];
#pragma unroll
      for (int i = 0; i < 4; ++i)
#pragma unroll
        for (int j = 0; j < 4; ++j)
          acc[i][j] = __builtin_amdgcn_mfma_f32_16x16x32_bf16(af[i], bfr[j],
                                                              acc[i][j], 0, 0, 0);
    }
  }

  // ---- epilogue: exp / stage to padded LDS -------------------------------
  __syncthreads();                     // staging LDS dead; switch to ep view
  int h = w >> 1, nh = w & 1;
  if (w < 4) {
    float sl[4][4];
#pragma unroll
    for (int i = 0; i < 4; ++i)
#pragma unroll
      for (int r = 0; r < 4; ++r) sl[i][r] = 0.f;
#pragma unroll
    for (int i = 0; i < 4; ++i)
#pragma unroll
      for (int j = 0; j < 4; ++j)
#pragma unroll
        for (int r = 0; r < 4; ++r) {
          float e = __expf(acc[i][j][r]);
          sl[i][r] += e;
          sm.ep.ek[wm + i * 16 + quad * 4 + r][wn + j * 16 + l16] = f2b(e);
        }
#pragma unroll
    for (int i = 0; i < 4; ++i)
#pragma unroll
      for (int r = 0; r < 4; ++r) {
        float v = sl[i][r];
        v += __shfl_xor(v, 1);
        v += __shfl_xor(v, 2);
        v += __shfl_xor(v, 4);
        v += __shfl_xor(v, 8);
        if (l16 == 0) sm.ep.sred[nh][wm + i * 16 + quad * 4 + r] = v;
      }
  } else {
#pragma unroll
    for (int i = 0; i < 4; ++i)
#pragma unroll
      for (int j = 0; j < 4; ++j)
#pragma unroll
        for (int r = 0; r < 4; ++r)
          sm.ep.vv[wm - 128 + i * 16 + quad * 4 + r][wn + j * 16 + l16] =
              f2b(acc[i][j][r]);
  }
  __syncthreads();
  if (t < 128)
    atomicAdd(&sv[(size_t)b * 128 + t], sm.ep.sred[0][t] + sm.ep.sred[1][t]);

  // ---- partial context: wave w -> head h = w>>1, spatial half nh = w&1 ----
  f32x4 c2[2][2];
#pragma unroll
  for (int i = 0; i < 2; ++i)
#pragma unroll
    for (int j = 0; j < 2; ++j)
#pragma unroll
      for (int r = 0; r < 4; ++r) c2[i][j][r] = 0.f;
#pragma unroll
  for (int kk = 0; kk < 2; ++kk) {
    bf16x8 ae[2], be[2];
#pragma unroll
    for (int i = 0; i < 2; ++i)
      ae[i] = *(const bf16x8*)&sm.ep.ek[h * 32 + i * 16 + l16][nh * 64 + kk * 32 + quad * 8];
#pragma unroll
    for (int j = 0; j < 2; ++j)
      be[j] = *(const bf16x8*)&sm.ep.vv[h * 32 + j * 16 + l16][nh * 64 + kk * 32 + quad * 8];
#pragma unroll
    for (int i = 0; i < 2; ++i)
#pragma unroll
      for (int j = 0; j < 2; ++j)
        c2[i][j] = __builtin_amdgcn_mfma_f32_16x16x32_bf16(ae[i], be[j], c2[i][j], 0, 0, 0);
  }
  __syncthreads();                     // ek/vv reads done; alias cred
  if (nh == 0) {
#pragma unroll
    for (int i = 0; i < 2; ++i)
#pragma unroll
      for (int j = 0; j < 2; ++j)
#pragma unroll
        for (int r = 0; r < 4; ++r)
          sm.cred[h * 1024 + (i * 16 + quad * 4 + r) * 32 + j * 16 + l16] = c2[i][j][r];
  }
  __syncthreads();
  if (nh == 1) {
#pragma unroll
    for (int i = 0; i < 2; ++i)
#pragma unroll
      for (int j = 0; j < 2; ++j)
#pragma unroll
        for (int r = 0; r < 4; ++r)
          sm.cred[h * 1024 + (i * 16 + quad * 4 + r) * 32 + j * 16 + l16] += c2[i][j][r];
  }
  __syncthreads();
  float* ctxb = ctx + (size_t)b * 4096;
#pragma unroll
  for (int u = 0; u < 8; ++u)
    atomicAdd(&ctxb[t + u * 512], sm.cred[t + u * 512]);
}

// ---------------------------------------------------------------------------
// K4: MFMA fold. grid 64 = (b,h), 256 thr (4 waves). wf[o][h*32+d] =
// sum_e outw[o][h*32+e] * (ctx[d][e]/s_d + bv[e]) as a 256x32x32 GEMM:
// one 16x16x32 MFMA per (o-frag, d-frag) -> 8 MFMAs/wave. Coalesced
// fragment loads (8 floats/lane). btp[b][h][o] = sum_d wf*bq via shfl
// reduce. wf -> LDS restage -> vectorized global stores.
// ---------------------------------------------------------------------------
__global__ __launch_bounds__(256) void fold_mfma_kernel(
    const float* __restrict__ ctx, const float* __restrict__ sv,
    const float* __restrict__ outw, const float* __restrict__ qkvb,
    u16* __restrict__ wf, float* __restrict__ btp)
{
  int b = blockIdx.x >> 2, h = blockIdx.x & 3;
  int t = threadIdx.x;
  int lane = t & 63, w = t >> 6;
  int quad = lane >> 4, l16 = lane & 15;
  __shared__ __align__(16) u16 wfl[256][40];

  // v-bias slice for this lane's k-range (e = quad*8 .. +8)
  float bv8[8];
#pragma unroll
  for (int e = 0; e < 8; ++e) bv8[e] = qkvb[256 + h * 32 + quad * 8 + e];

  // B-fragments: rows d = j*16+l16, K = e (32, covered by 4 quads x 8)
  bf16x8 bf[2];
#pragma unroll
  for (int j = 0; j < 2; ++j) {
    int d = j * 16 + l16;
    float si = 1.f / sv[(size_t)b * 128 + h * 32 + d];
    const float* cp = ctx + (size_t)b * 4096 + h * 1024 + d * 32 + quad * 8;
    float4 c0 = *(const float4*)(cp);
    float4 c1 = *(const float4*)(cp + 4);
    float cv[8] = {c0.x, c0.y, c0.z, c0.w, c1.x, c1.y, c1.z, c1.w};
    u16* bp = (u16*)&bf[j];
#pragma unroll
    for (int e = 0; e < 8; ++e) bp[e] = f2b(cv[e] * si + bv8[e]);
  }

  // A-fragments (outw rows o = w*64 + i*16 + l16) + MFMA (K=32, acc from 0)
  f32x4 acc[4][2];
#pragma unroll
  for (int i = 0; i < 4; ++i) {
    int o = w * 64 + i * 16 + l16;
    const float* ap = outw + (size_t)o * HID_ + h * 32 + quad * 8;
    float4 a0 = *(const float4*)(ap);
    float4 a1 = *(const float4*)(ap + 4);
    float av[8] = {a0.x, a0.y, a0.z, a0.w, a1.x, a1.y, a1.z, a1.w};
    bf16x8 af;
    u16* app = (u16*)&af;
#pragma unroll
    for (int e = 0; e < 8; ++e) app[e] = f2b(av[e]);
    f32x4 z;
#pragma unroll
    for (int r = 0; r < 4; ++r) z[r] = 0.f;
#pragma unroll
    for (int j = 0; j < 2; ++j)
      acc[i][j] = __builtin_amdgcn_mfma_f32_16x16x32_bf16(af, bf[j], z, 0, 0, 0);
  }

  // btp: per o, sum_d wf[o][d]*bq[h*32+d]; d = j*16+l16 -> shfl over l16
  float bqv[2];
#pragma unroll
  for (int j = 0; j < 2; ++j) bqv[j] = qkvb[h * 32 + j * 16 + l16];
#pragma unroll
  for (int i = 0; i < 4; ++i) {
#pragma unroll
    for (int r = 0; r < 4; ++r) {
      float v = acc[i][0][r] * bqv[0] + acc[i][1][r] * bqv[1];
      v += __shfl_xor(v, 1);
      v += __shfl_xor(v, 2);
      v += __shfl_xor(v, 4);
      v += __shfl_xor(v, 8);
      if (l16 == 0) {
        int o = w * 64 + i * 16 + quad * 4 + r;
        btp[((size_t)b * 4 + h) * 256 + o] = v;
      }
    }
  }

  // wf restage: C[o][d] -> LDS (row o, col d), then vectorized global store
#pragma unroll
  for (int i = 0; i < 4; ++i)
#pragma unroll
    for (int j = 0; j < 2; ++j)
#pragma unroll
      for (int r = 0; r < 4; ++r)
        wfl[w * 64 + i * 16 + quad * 4 + r][j * 16 + l16] = f2b(acc[i][j][r]);
  __syncthreads();
  int rr = t >> 2, rof = (t & 3) * 8;   // 4 threads/row x 16 B
#pragma unroll
  for (int it = 0; it < 4; ++it) {
    int o = it * 64 + rr;
    *(uint4*)(wf + ((size_t)b * C_ + o) * HID_ + h * 32 + rof) =
        *(const uint4*)&wfl[o][rof];
  }
}

// ---------------------------------------------------------------------------
// K5: Wtot fold GEMM (tiny, proven R3 structure). Wtot[b][o][c] =
// sum_d wf[b][o][d] * WqT[c][d], bf16 out. 128x128 tile, K=128. grid (2,2,16).
// ---------------------------------------------------------------------------
__global__ __launch_bounds__(256) void wtot_gemm_kernel(
    const u16* __restrict__ wfp, const u16* __restrict__ wqT,
    u16* __restrict__ wtot)
{
  const int K = HID_;
  int nt = blockIdx.x, mt = blockIdx.y, b = blockIdx.z;
  const u16* Ab = wfp + (size_t)b * C_ * HID_ + (size_t)mt * 128 * K;
  const u16* Bb = wqT + (size_t)nt * 128 * K;
  __shared__ __align__(16) u16 lA[128 * 64];
  __shared__ __align__(16) u16 lB[128 * 64];
  int t = threadIdx.x;
  int lane = t & 63, w = t >> 6;
  int quad = lane >> 4, l16 = lane & 15;
  int wm = (w >> 1) * 64, wn = (w & 1) * 64;
  f32x4 acc[4][4];
#pragma unroll
  for (int i = 0; i < 4; ++i)
#pragma unroll
    for (int j = 0; j < 4; ++j)
#pragma unroll
      for (int r = 0; r < 4; ++r) acc[i][j][r] = 0.f;

  for (int k0 = 0; k0 < K; k0 += 64) {
    __syncthreads();
#pragma unroll
    for (int q = 0; q < 4; ++q) {
      int ch = q * 256 + t;
      int row = ch >> 3, off = (ch & 7) * 8;
      __builtin_amdgcn_global_load_lds(
          (const __attribute__((address_space(1))) void*)(Ab + (size_t)row * K + k0 + off),
          (__attribute__((address_space(3))) void*)(lA + ch * 8), 16, 0, 0);
      __builtin_amdgcn_global_load_lds(
          (const __attribute__((address_space(1))) void*)(Bb + (size_t)row * K + k0 + off),
          (__attribute__((address_space(3))) void*)(lB + ch * 8), 16, 0, 0);
    }
    __syncthreads();
    const bf16x8* A8 = (const bf16x8*)lA;
    const bf16x8* B8 = (const bf16x8*)lB;
#pragma unroll
    for (int kk = 0; kk < 2; ++kk) {
      bf16x8 af[4], bfr[4];
#pragma unroll
      for (int i = 0; i < 4; ++i) af[i]  = A8[(wm + i * 16 + l16) * 8 + kk * 4 + quad];
#pragma unroll
      for (int j = 0; j < 4; ++j) bfr[j] = B8[(wn + j * 16 + l16) * 8 + kk * 4 + quad];
#pragma unroll
      for (int i = 0; i < 4; ++i)
#pragma unroll
        for (int j = 0; j < 4; ++j)
          acc[i][j] = __builtin_amdgcn_mfma_f32_16x16x32_bf16(af[i], bfr[j],
                                                              acc[i][j], 0, 0, 0);
    }
  }
  u16* Wb = wtot + (size_t)b * C_ * C_;
#pragma unroll
  for (int i = 0; i < 4; ++i) {
#pragma unroll
    for (int rg = 0; rg < 4; ++rg) {
      int o = mt * 128 + wm + i * 16 + quad * 4 + rg;
#pragma unroll
      for (int j = 0; j < 4; ++j) {
        int c = nt * 128 + wn + j * 16 + l16;
        Wb[(size_t)o * C_ + c] = f2b(acc[i][j][rg]);
      }
    }
  }
}

// ---------------------------------------------------------------------------
// K6: final GEMM. out = Wtot(bf16 256x256) @ xn_t^T (+outb+btp), fp32 out.
// 128x128 tile, BK=64, K=256. grid (32, 2, 16). Swapped MFMA operands:
// acc rows = n -> float4 stores.
// ---------------------------------------------------------------------------
__global__ __launch_bounds__(256) void out_gemm_kernel(
    const u16* __restrict__ wtot, const u16* __restrict__ Bt,
    const float* __restrict__ outb, const float* __restrict__ btp,
    float* __restrict__ Cout)
{
  const int K = C_;
  int nt = blockIdx.x, mt = blockIdx.y, b = blockIdx.z;
  const u16* Ab = wtot + (size_t)b * C_ * C_ + (size_t)mt * 128 * K;
  const u16* Bb = Bt + (size_t)b * HW_ * C_ + (size_t)nt * 128 * K;
  __shared__ __align__(16) u16 lA[128 * 64];
  __shared__ __align__(16) u16 lB[128 * 64];
  int t = threadIdx.x;
  int lane = t & 63, w = t >> 6;
  int quad = lane >> 4, l16 = lane & 15;
  int wm = (w >> 1) * 64, wn = (w & 1) * 64;
  f32x4 acc[4][4];                       // [j: n-frag][i: o-frag]
#pragma unroll
  for (int j = 0; j < 4; ++j)
#pragma unroll
    for (int i = 0; i < 4; ++i)
#pragma unroll
      for (int r = 0; r < 4; ++r) acc[j][i][r] = 0.f;

  for (int k0 = 0; k0 < K; k0 += 64) {
    __syncthreads();
#pragma unroll
    for (int q = 0; q < 4; ++q) {
      int ch = q * 256 + t;
      int row = ch >> 3, off = (ch & 7) * 8;
      __builtin_amdgcn_global_load_lds(
          (const __attribute__((address_space(1))) void*)(Ab + (size_t)row * K + k0 + off),
          (__attribute__((address_space(3))) void*)(lA + ch * 8), 16, 0, 0);
      __builtin_amdgcn_global_load_lds(
          (const __attribute__((address_space(1))) void*)(Bb + (size_t)row * K + k0 + off),
          (__attribute__((address_space(3))) void*)(lB + ch * 8), 16, 0, 0);
    }
    __syncthreads();
    const bf16x8* A8 = (const bf16x8*)lA;
    const bf16x8* B8 = (const bf16x8*)lB;
#pragma unroll
    for (int kk = 0; kk < 2; ++kk) {
      bf16x8 af[4], bfr[4];
#pragma unroll
      for (int i = 0; i < 4; ++i) af[i]  = A8[(wm + i * 16 + l16) * 8 + kk * 4 + quad];
#pragma unroll
      for (int j = 0; j < 4; ++j) bfr[j] = B8[(wn + j * 16 + l16) * 8 + kk * 4 + quad];
#pragma unroll
      for (int j = 0; j < 4; ++j)
#pragma unroll
        for (int i = 0; i < 4; ++i)
          acc[j][i] = __builtin_amdgcn_mfma_f32_16x16x32_bf16(bfr[j], af[i],
                                                              acc[j][i], 0, 0, 0);
    }
  }
  // D[row = n-local (quad*4+r)][col = o-local (l16)]
#pragma unroll
  for (int i = 0; i < 4; ++i) {
    int o = mt * 128 + wm + i * 16 + l16;
    float bo = outb[o]
             + btp[((size_t)b * 4 + 0) * 256 + o]
             + btp[((size_t)b * 4 + 1) * 256 + o]
             + btp[((size_t)b * 4 + 2) * 256 + o]
             + btp[((size_t)b * 4 + 3) * 256 + o];
    size_t rowbase = (size_t)b * C_ * HW_ + (size_t)o * HW_;
#pragma unroll
    for (int j = 0; j < 4; ++j) {
      int n0 = nt * 128 + wn + j * 16 + quad * 4;
      float4 v = make_float4(acc[j][i][0] + bo, acc[j][i][1] + bo,
                             acc[j][i][2] + bo, acc[j][i][3] + bo);
      *(float4*)(Cout + rowbase + n0) = v;
    }
  }
}

// ---------------------------------------------------------------------------
extern "C" void kernel_launch(void* const* d_in, const int* in_sizes, int n_in,
                              void* d_out, int out_size, void* d_ws, size_t ws_size,
                              hipStream_t stream)
{
  const float* x    = (const float*)d_in[0];
  const float* gnw  = (const float*)d_in[1];
  const float* gnb  = (const float*)d_in[2];
  const float* qkvw = (const float*)d_in[3];
  const float* qkvb = (const float*)d_in[4];
  const float* outw = (const float*)d_in[5];
  const float* outb = (const float*)d_in[6];

  char* p = (char*)d_ws;
  float* scale  = (float*)p;            p += (size_t)B_ * C_ * 4;
  float* shiftv = (float*)p;            p += (size_t)B_ * C_ * 4;
  u16* cqkvw = (u16*)p;                 p += (size_t)QR_ * C_ * 2;
  u16* wqT   = (u16*)p;                 p += (size_t)C_ * HID_ * 2;
  u16* xn_t  = (u16*)p;                 p += (size_t)B_ * HW_ * C_ * 2;
  u16* wf    = (u16*)p;                 p += (size_t)B_ * C_ * HID_ * 2;
  u16* wtot  = (u16*)p;                 p += (size_t)B_ * C_ * C_ * 2;
  float* ctxs = (float*)p;              p += (size_t)67584 * 4;   // ctx 65536 + s 2048
  float* btp  = (float*)p;
  float* ctx = ctxs;
  float* sv  = ctxs + 65536;

  gn_stats_conv_kernel<<<675, 256, 0, stream>>>(x, gnw, gnb, scale, shiftv,
                                                qkvw, cqkvw, wqT, ctxs);
  gn_transpose_kernel<<<dim3(32, 4, 16), 256, 0, stream>>>(x, xn_t, scale, shiftv);
  kv_ctx_kernel<<<dim3(32, 16), 512, 0, stream>>>(cqkvw + 128 * C_, xn_t, ctx, sv);
  fold_mfma_kernel<<<64, 256, 0, stream>>>(ctx, sv, outw, qkvb, wf, btp);
  wtot_gemm_kernel<<<dim3(2, 2, 16), 256, 0, stream>>>(wf, wqT, wtot);
  out_gemm_kernel<<<dim3(32, 2, 16), 256, 0, stream>>>(wtot, xn_t, outb, btp,
                                                       (float*)d_out);
}